// Round 2
// baseline (1075.887 us; speedup 1.0000x reference)
//
#include <hip/hip_runtime.h>
#include <math.h>

#define BB 64
#define DD 8732
#define CC 81
#define NN 50
#define TROWS 64                    // rows per tile
#define TFL4  1296                  // 64*81/4 float4 per tile (20736 B)
#define CE_GRID 1024                // 4 blocks/CU
#define NTILES (BB * DD / TROWS)    // 8732 exactly

// ---------------- k_fused: match + CE + smooth-L1 in one streaming pass ------
// Tile = 64 rows of conf_data (20736 B) double-buffered through named regs
// r0..r5 into LDS (unchanged pipeline from the passing k_ce). Each 16-lane
// group owns one row (b,d) and ADDITIONALLY computes the 50-box best-IoU
// match for that row: lane s handles n = s, s+16, s+32 (+s+48 for s<2), then
// a lexicographic (max iou, min n) xor-reduce reproduces jnp.argmax's
// first-max exactly (same IEEE f32 divide, same operand order, exact ties ->
// lower n). conf_t never touches global memory; num_pos / loss_l accumulate
// here. k_match is deleted entirely.
__global__ __launch_bounds__(256, 4) void k_fused(
    const float* __restrict__ conf_data,  // [B,D,C]
    const float* __restrict__ loc_data,   // [B,D,4]
    const float* __restrict__ dboxes,     // [D,4]
    const float* __restrict__ tboxes,     // [B,N,4]
    const int*   __restrict__ tlabels,    // [B,N]
    float* __restrict__ ce_mined,         // [B*D] (positives zeroed)
    int*   __restrict__ num_pos,          // [B]  (pre-zeroed)
    float* __restrict__ acc)              // [0]=loss_l, [1]=loss_c (pre-zeroed)
{
    __shared__ float4 sbuf[TFL4];             // 20736 B
    const int tid  = threadIdx.x;
    const int lane = tid & 63;
    const int w    = tid >> 6;        // wave in block (0..3)
    const int q    = lane >> 4;       // quarter (0..3)
    const int s    = lane & 15;       // sublane within quarter

    const float4* __restrict__ dbx = (const float4*)dboxes;
    const float4* __restrict__ tbx = (const float4*)tboxes;

    float4 r0, r1, r2, r3, r4, r5;
    float lc = 0.0f;                  // pos-CE partial
    float ll = 0.0f;                  // smooth-L1 partial

    int t = blockIdx.x;
    {
        const float4* src = (const float4*)conf_data + (size_t)t * TFL4;
        r0 = src[tid];
        r1 = src[tid + 256];
        r2 = src[tid + 512];
        r3 = src[tid + 768];
        r4 = src[tid + 1024];
        if (tid < 16) r5 = src[1280 + tid];
    }
    for (; t < NTILES; t += CE_GRID) {
        __syncthreads();                      // prior compute done; LDS reusable
        sbuf[tid]        = r0;                // vmcnt wait lands here
        sbuf[tid + 256]  = r1;
        sbuf[tid + 512]  = r2;
        sbuf[tid + 768]  = r3;
        sbuf[tid + 1024] = r4;
        if (tid < 16) sbuf[1280 + tid] = r5;
        const int tn = t + CE_GRID;
        if (tn < NTILES) {                    // issue next tile's loads NOW
            const float4* src = (const float4*)conf_data + (size_t)tn * TFL4;
            r0 = src[tid];
            r1 = src[tid + 256];
            r2 = src[tid + 512];
            r3 = src[tid + 768];
            r4 = src[tid + 1024];
            if (tid < 16) r5 = src[1280 + tid];
        }
        __syncthreads();                      // tile t visible in LDS

        const float* sb = (const float*)sbuf;
        #pragma unroll
        for (int i = 0; i < 4; i++) {
            const int lr = w * 16 + i * 4 + q;        // local row 0..63
            const int r  = t * TROWS + lr;            // global row = b*DD + d
            const int b  = r / DD;                    // magic-mul div
            const int d  = r - b * DD;

            // ---- match: best-IoU gt for prior d (spread over 16 lanes) ----
            const float4 db = dbx[d];                 // broadcast across group
            const float dx1 = db.x, dy1 = db.y, dx2 = db.z, dy2 = db.w;
            const float dArea = (dx1 - dx2) * (dy1 - dy2);
            float bIoU = -1.0f;
            int   bN   = 0;
            #pragma unroll
            for (int j = 0; j < 4; j++) {
                const int n = s + (j << 4);
                if (n < NN) {
                    const float4 tb4 = tbx[b * NN + n];
                    const float area = (tb4.x - tb4.z) * (tb4.y - tb4.w);
                    const float lx = fmaxf(tb4.x, dx1), ly = fmaxf(tb4.y, dy1);
                    const float rx = fminf(tb4.z, dx2), ry = fminf(tb4.w, dy2);
                    const float ww = fmaxf(rx - lx, 0.0f);
                    const float hh = fmaxf(ry - ly, 0.0f);
                    const float inter = ww * hh;
                    const float iou = inter / (area + dArea - inter); // IEEE, ref order
                    if (iou > bIoU) { bIoU = iou; bN = n; }  // in-lane first-max
                }
            }
            #pragma unroll
            for (int off = 1; off < 16; off <<= 1) {  // lex (max iou, min n)
                const float oI = __shfl_xor(bIoU, off);
                const int   oN = __shfl_xor(bN, off);
                if (oI > bIoU || (oI == bIoU && oN < bN)) { bIoU = oI; bN = oN; }
            }
            int ct = 0;
            if (!(bIoU < 0.5f)) ct = tlabels[b * NN + bN] + 1;
            const bool pos = (ct > 0);

            // ---- smooth-L1 for positive rows (one lane per row) ----
            if (pos && s == 0) {
                const float4 tb4 = tbx[b * NN + bN];
                const float bx1 = tb4.x, by1 = tb4.y, bx2 = tb4.z, by2 = tb4.w;
                const float dw = dx2 - dx1, dh = dy2 - dy1;
                const float t0 = ((bx1 - dx1) + (bx2 - dx2)) * 0.5f * 10.0f / dw;
                const float t1 = ((by1 - dy1) + (by2 - dy2)) * 0.5f * 10.0f / dh;
                const float t2 = __logf((bx2 - bx1) / dw) * 5.0f;
                const float t3 = __logf((by2 - by1) / dh) * 5.0f;
                const float4 ld = ((const float4*)loc_data)[(size_t)b * DD + d];
                float xs[4] = {ld.x - t0, ld.y - t1, ld.z - t2, ld.w - t3};
                #pragma unroll
                for (int k = 0; k < 4; k++) {
                    float ax = fabsf(xs[k]);
                    ll += (ax < 1.0f) ? 0.5f * xs[k] * xs[k] : ax - 0.5f;
                }
                atomicAdd(&num_pos[b], 1);            // fire-and-forget
            }

            // ---- CE over the 81 logits (unchanged from passing k_ce) ----
            const float* row = sb + lr * CC;
            float x0 = row[s];
            float x1 = row[s + 16];
            float x2 = row[s + 32];
            float x3 = row[s + 48];
            float x4 = row[s + 64];
            float x5 = (s == 0) ? row[80] : 0.0f;

            float e = __expf(x0) + __expf(x1) + __expf(x2) + __expf(x3) + __expf(x4);
            if (s == 0) e += __expf(x5);

            const int k  = ct >> 4;
            const int sl = ct & 15;
            float xv = (k == 0) ? x0 : (k == 1) ? x1 : (k == 2) ? x2
                     : (k == 3) ? x3 : (k == 4) ? x4 : x5;
            float v = (s == sl) ? xv : 0.0f;

            #pragma unroll
            for (int off = 1; off < 16; off <<= 1) {
                e += __shfl_xor(e, off);
                v += __shfl_xor(v, off);
            }
            if (s == 0) {
                float ce = fmaxf(__logf(e) - v, 0.0f);
                ce_mined[r] = pos ? 0.0f : ce;
                if (pos) lc += ce;
            }
        }
    }
    #pragma unroll
    for (int off = 32; off > 0; off >>= 1) {
        lc += __shfl_down(lc, off);
        ll += __shfl_down(ll, off);
    }
    if (lane == 0) {
        if (lc != 0.0f) atomicAdd(&acc[1], lc);
        if (ll != 0.0f) atomicAdd(&acc[0], ll);
    }
}

// ---------------- k_tail: per-batch top-K sum + last-block finalize ----------
// K-th largest via binary search on float bit patterns (values >= 0);
// sum(topK) = sum(v > vK) + (K - cnt_gt)*vK -- exact, tie-order invariant.
__global__ __launch_bounds__(256) void k_tail(
    const float* __restrict__ ce_mined,   // [B*D]
    const int*   __restrict__ num_pos,    // [B]
    float* __restrict__ acc,              // [2]
    int*   __restrict__ done,             // [1]  (pre-zeroed)
    float* __restrict__ out)              // [2]
{
    const int b   = blockIdx.x;
    const int tid = threadIdx.x;
    const int K   = min(3 * num_pos[b], DD);
    __shared__ int   s_cnt;
    __shared__ float s_sum;

    const float* rowm = ce_mined + (size_t)b * DD;
    unsigned vv[35];                      // 35*256 = 8960 >= 8732
    #pragma unroll
    for (int j = 0; j < 35; j++) {
        int i = tid + j * 256;
        vv[j] = (i < DD) ? __float_as_uint(rowm[i]) : 0u;
    }

    if (K > 0) {                          // uniform per block
        unsigned lo = 0u, hi = 0x7F800000u;
        while (lo < hi) {
            unsigned mid = lo + ((hi - lo) >> 1);
            int c = 0;
            #pragma unroll
            for (int j = 0; j < 35; j++) c += (vv[j] > mid) ? 1 : 0;
            for (int off = 32; off > 0; off >>= 1) c += __shfl_down(c, off);
            if (tid == 0) s_cnt = 0;
            __syncthreads();
            if ((tid & 63) == 0) atomicAdd(&s_cnt, c);
            __syncthreads();
            if (s_cnt >= K) lo = mid + 1; else hi = mid;
            __syncthreads();
        }
        const unsigned ustar = lo;
        const float thr = __uint_as_float(ustar);
        float sum = 0.0f; int cgt = 0;
        #pragma unroll
        for (int j = 0; j < 35; j++) {
            if (vv[j] > ustar) { sum += __uint_as_float(vv[j]); cgt++; }
        }
        for (int off = 32; off > 0; off >>= 1) {
            sum += __shfl_down(sum, off);
            cgt += __shfl_down(cgt, off);
        }
        if (tid == 0) { s_sum = 0.0f; s_cnt = 0; }
        __syncthreads();
        if ((tid & 63) == 0) { atomicAdd(&s_sum, sum); atomicAdd(&s_cnt, cgt); }
        __syncthreads();
        if (tid == 0) atomicAdd(&acc[1], s_sum + (float)(K - s_cnt) * thr);
    }
    __syncthreads();

    if (tid == 0) {
        __threadfence();                       // my acc[1] add visible before done++
        int old = atomicAdd(done, 1);          // device-scope
        if (old == BB - 1) {                   // last block: all adds complete
            __threadfence();
            int np = 0;
            for (int i = 0; i < BB; i++) np += num_pos[i];
            float l0 = acc[0];
            float l1 = atomicAdd(&acc[1], 0.0f);            // atomic read (RMW)
            float Nt = (float)np;
            out[0] = l0 / Nt;
            out[1] = l1 / Nt;
        }
    }
}

extern "C" void kernel_launch(void* const* d_in, const int* in_sizes, int n_in,
                              void* d_out, int out_size, void* d_ws, size_t ws_size,
                              hipStream_t stream) {
    const float* loc_data  = (const float*)d_in[0];  // [64,8732,4]
    const float* conf_data = (const float*)d_in[1];  // [64,8732,81]
    const float* dboxes    = (const float*)d_in[2];  // [8732,4]
    const float* tboxes    = (const float*)d_in[3];  // [64,50,4]
    const int*   tlabels   = (const int*)d_in[4];    // [64,50]
    float* out = (float*)d_out;

    // ws: ce_mined[B*D] | num_pos[64] | acc[2] | done[1]
    float* ce_mined = (float*)d_ws;
    int*   num_pos  = (int*)(ce_mined + (size_t)BB * DD);
    float* acc      = (float*)(num_pos + BB);
    int*   done     = (int*)(acc + 2);

    hipMemsetAsync(num_pos, 0, (BB + 3) * sizeof(int), stream);  // np + acc + done

    hipLaunchKernelGGL(k_fused, dim3(CE_GRID), dim3(256), 0, stream,
                       conf_data, loc_data, dboxes, tboxes, tlabels,
                       ce_mined, num_pos, acc);
    hipLaunchKernelGGL(k_tail, dim3(BB), dim3(256), 0, stream,
                       ce_mined, num_pos, acc, done, out);
}

// Round 4
// 318.336 us; speedup vs baseline: 3.3797x; 3.3797x over previous
//
#include <hip/hip_runtime.h>
#include <math.h>

#define BB 64
#define DD 8732
#define CC 81
#define NN 50
#define TROWS 64                    // rows per tile
#define TFL4  1296                  // 64*81/4 float4 per tile (20736 B)
#define CE_GRID 1024                // stream blocks: 4 per CU
#define MBX 35                      // match x-chunks: ceil(8732/256)
#define NTILES (BB * DD / TROWS)    // 8732 exactly

// ---------------- k_main: LSE stream (blocks < CE_GRID) || match (rest) -----
// Stream part: verbatim R1 k_ce pipeline (named-reg prefetch -> LDS), but
// computes ONLY lse[r] = log(sum exp) with the identical e-summation order
// (bit-exact vs R1). No conf_t dependency -> runs concurrently with match.
// Match part: verbatim R1 k_match body (proven). Writes conf_t[r] and a
// per-block smooth-L1 partial to lpart[bid2] (plain store, no atomics, no
// pre-zeroing). Block 0 additionally zeroes `done` for k_tail (kernel
// boundary makes the store visible) -- this was R3's bug: an un-zeroed
// done counter fired the finalizer early.
__global__ __launch_bounds__(256, 8) void k_main(
    const float* __restrict__ conf_data,  // [B,D,C]
    const float* __restrict__ loc_data,   // [B,D,4]
    const float* __restrict__ dboxes,     // [D,4]
    const float* __restrict__ tboxes,     // [B,N,4]
    const int*   __restrict__ tlabels,    // [B,N]
    float* __restrict__ lse,              // [B*D] out
    unsigned char* __restrict__ conf_t,   // [B*D] out
    float* __restrict__ lpart,            // [MBX*BB] out: smooth-L1 partials
    unsigned* __restrict__ done)          // [1] zeroed here each launch
{
    __shared__ float4 sbuf[TFL4];         // 20736 B (allocated for all blocks)
    __shared__ float  s_m[4];
    const int tid = threadIdx.x;

    if (blockIdx.x == 0 && tid == 0) *done = 0u;   // reset for k_tail

    if (blockIdx.x < CE_GRID) {
        // ---------------- streaming LSE ----------------
        const int lane = tid & 63;
        const int w    = tid >> 6;        // wave in block (0..3)
        const int q    = lane >> 4;       // quarter (0..3)
        const int s    = lane & 15;       // sublane within quarter

        float4 r0, r1, r2, r3, r4, r5;
        int t = blockIdx.x;
        {
            const float4* src = (const float4*)conf_data + (size_t)t * TFL4;
            r0 = src[tid];
            r1 = src[tid + 256];
            r2 = src[tid + 512];
            r3 = src[tid + 768];
            r4 = src[tid + 1024];
            if (tid < 16) r5 = src[1280 + tid];
        }
        for (; t < NTILES; t += CE_GRID) {
            __syncthreads();                      // prior compute done
            sbuf[tid]        = r0;                // vmcnt wait lands here
            sbuf[tid + 256]  = r1;
            sbuf[tid + 512]  = r2;
            sbuf[tid + 768]  = r3;
            sbuf[tid + 1024] = r4;
            if (tid < 16) sbuf[1280 + tid] = r5;
            const int tn = t + CE_GRID;
            if (tn < NTILES) {                    // issue next tile's loads NOW
                const float4* src = (const float4*)conf_data + (size_t)tn * TFL4;
                r0 = src[tid];
                r1 = src[tid + 256];
                r2 = src[tid + 512];
                r3 = src[tid + 768];
                r4 = src[tid + 1024];
                if (tid < 16) r5 = src[1280 + tid];
            }
            __syncthreads();                      // tile t visible in LDS

            const float* sb = (const float*)sbuf;
            #pragma unroll
            for (int i = 0; i < 4; i++) {
                const int lr = w * 16 + i * 4 + q;        // local row 0..63
                const float* row = sb + lr * CC;
                float x0 = row[s];
                float x1 = row[s + 16];
                float x2 = row[s + 32];
                float x3 = row[s + 48];
                float x4 = row[s + 64];
                float x5 = (s == 0) ? row[80] : 0.0f;

                float e = __expf(x0) + __expf(x1) + __expf(x2) + __expf(x3) + __expf(x4);
                if (s == 0) e += __expf(x5);
                #pragma unroll
                for (int off = 1; off < 16; off <<= 1) e += __shfl_xor(e, off);
                if (s == 0) lse[t * TROWS + lr] = __logf(e);
            }
        }
    } else {
        // ---------------- match (R1 k_match body) ----------------
        const int bid2 = blockIdx.x - CE_GRID;    // 0..MBX*BB-1
        const int b    = bid2 / MBX;
        const int bx   = bid2 - b * MBX;
        const int d    = bx * 256 + tid;
        const bool active = (d < DD);
        const int dc   = active ? d : (DD - 1);   // clamp: uniform execution

        const float* __restrict__ tb = tboxes + b * (NN * 4);  // uniform -> s_load

        const float4 db = ((const float4*)dboxes)[dc];
        const float dx1 = db.x, dy1 = db.y, dx2 = db.z, dy2 = db.w;
        const float dArea = (dx1 - dx2) * (dy1 - dy2);

        float bestIoU = -1.0f;
        int   bestN   = 0;
        #pragma unroll 10
        for (int n = 0; n < NN; n++) {
            const float tx1 = tb[n * 4 + 0];
            const float ty1 = tb[n * 4 + 1];
            const float tx2 = tb[n * 4 + 2];
            const float ty2 = tb[n * 4 + 3];
            const float area = (tx1 - tx2) * (ty1 - ty2);   // == reference _area
            const float lx = fmaxf(tx1, dx1), ly = fmaxf(ty1, dy1);
            const float rx = fminf(tx2, dx2), ry = fminf(ty2, dy2);
            const float w2 = fmaxf(rx - lx, 0.0f), h2 = fmaxf(ry - ly, 0.0f);
            const float inter = w2 * h2;
            const float iou = inter / (area + dArea - inter);  // IEEE, ref order
            if (iou > bestIoU) { bestIoU = iou; bestN = n; }   // first-max
        }

        int ct = 0;
        if (!(bestIoU < 0.5f)) ct = tlabels[b * NN + bestN] + 1;
        const bool pos = active && (ct > 0);
        if (active) conf_t[(size_t)b * DD + d] = (unsigned char)ct;

        float ll = 0.0f;
        if (pos) {
            const float bx1 = tb[bestN * 4 + 0], by1 = tb[bestN * 4 + 1];
            const float bx2 = tb[bestN * 4 + 2], by2 = tb[bestN * 4 + 3];
            const float dw = dx2 - dx1, dh = dy2 - dy1;
            const float t0 = ((bx1 - dx1) + (bx2 - dx2)) * 0.5f * 10.0f / dw;
            const float t1 = ((by1 - dy1) + (by2 - dy2)) * 0.5f * 10.0f / dh;
            const float t2 = __logf((bx2 - bx1) / dw) * 5.0f;
            const float t3 = __logf((by2 - by1) / dh) * 5.0f;
            const float4 ld = ((const float4*)loc_data)[(size_t)b * DD + d];
            float xs[4] = {ld.x - t0, ld.y - t1, ld.z - t2, ld.w - t3};
            #pragma unroll
            for (int k = 0; k < 4; k++) {
                float ax = fabsf(xs[k]);
                ll += (ax < 1.0f) ? 0.5f * xs[k] * xs[k] : ax - 0.5f;
            }
        }
        for (int off = 32; off > 0; off >>= 1) ll += __shfl_down(ll, off);
        if ((tid & 63) == 0) s_m[tid >> 6] = ll;
        __syncthreads();
        if (tid == 0) lpart[bid2] = s_m[0] + s_m[1] + s_m[2] + s_m[3];
    }
}

// ---------------- k_tail: CE gather + pos stats + top-K + finalize -----------
// Per batch b: recompute ce = fmax(lse - x_ct, 0) bit-identically (lse bits
// round-trip global memory; x_ct gathered straight from conf_data). Counts
// num_pos locally from conf_t (no atomics, no memset). Top-K via the proven
// binary search on float bit patterns. done is zeroed by k_main each launch;
// the LAST arriving block (old == BB-1) finalizes -- R1's proven pattern.
__global__ __launch_bounds__(256) void k_tail(
    const float* __restrict__ lse,        // [B*D]
    const unsigned char* __restrict__ conf_t,
    const float* __restrict__ conf_data,  // [B,D,C]
    const float* __restrict__ lpart,      // [MBX*BB]
    int*   __restrict__ num_pos,          // [B]  (plain stores)
    float* __restrict__ cpart,            // [B]  (plain stores)
    unsigned* __restrict__ done,          // [1]  (zeroed by k_main)
    float* __restrict__ out)              // [2]
{
    const int b   = blockIdx.x;
    const int tid = threadIdx.x;
    __shared__ int   s_cnt;
    __shared__ float s_sum;
    __shared__ float s_lsum;
    __shared__ int   s_np;

    // grand-total loss_l (redundant per block; 9 loads/thread)
    float lp = 0.0f;
    for (int j = tid; j < MBX * BB; j += 256) lp += lpart[j];
    for (int off = 32; off > 0; off >>= 1) lp += __shfl_down(lp, off);
    if (tid == 0) { s_lsum = 0.0f; s_np = 0; }
    __syncthreads();
    if ((tid & 63) == 0) atomicAdd(&s_lsum, lp);

    // per-row CE: gather x_ct, rebuild ce bit-exactly; count positives
    unsigned vv[35];                      // 35*256 = 8960 >= 8732
    float lcp = 0.0f;                     // positive-row CE partial
    int   myp = 0;
    #pragma unroll
    for (int j = 0; j < 35; j++) {
        const int i = tid + j * 256;
        if (i < DD) {
            const size_t r = (size_t)b * DD + i;
            const int   ct = conf_t[r];
            const float x  = conf_data[r * CC + (size_t)ct];
            const float ce = fmaxf(lse[r] - x, 0.0f);
            if (ct > 0) { lcp += ce; myp++; vv[j] = 0u; }
            else        { vv[j] = __float_as_uint(ce); }
        } else vv[j] = 0u;
    }
    for (int off = 32; off > 0; off >>= 1) myp += __shfl_down(myp, off);
    if ((tid & 63) == 0) atomicAdd(&s_np, myp);
    __syncthreads();
    const int np = s_np;
    const int K  = min(3 * np, DD);
    if (tid == 0) num_pos[b] = np;

    // K-th largest via binary search on bit patterns (values >= 0)
    unsigned ustar = 0xFFFFFFFFu;
    float    thr   = 0.0f;
    if (K > 0) {
        unsigned lo = 0u, hi = 0x7F800000u;
        while (lo < hi) {
            unsigned mid = lo + ((hi - lo) >> 1);
            int c = 0;
            #pragma unroll
            for (int j = 0; j < 35; j++) c += (vv[j] > mid) ? 1 : 0;
            for (int off = 32; off > 0; off >>= 1) c += __shfl_down(c, off);
            if (tid == 0) s_cnt = 0;
            __syncthreads();
            if ((tid & 63) == 0) atomicAdd(&s_cnt, c);
            __syncthreads();
            if (s_cnt >= K) lo = mid + 1; else hi = mid;
            __syncthreads();
        }
        ustar = lo;
        thr   = __uint_as_float(ustar);
    }

    // block loss_c partial = pos CE + sum(v > thr) + (K - cnt_gt)*thr
    float sum = lcp;
    int   cgt = 0;
    if (K > 0) {
        #pragma unroll
        for (int j = 0; j < 35; j++) {
            if (vv[j] > ustar) { sum += __uint_as_float(vv[j]); cgt++; }
        }
    }
    for (int off = 32; off > 0; off >>= 1) {
        sum += __shfl_down(sum, off);
        cgt += __shfl_down(cgt, off);
    }
    if (tid == 0) { s_sum = 0.0f; s_cnt = 0; }
    __syncthreads();
    if ((tid & 63) == 0) { atomicAdd(&s_sum, sum); atomicAdd(&s_cnt, cgt); }
    __syncthreads();
    if (tid == 0) {
        cpart[b] = s_sum + ((K > 0) ? (float)(K - s_cnt) * thr : 0.0f);
        __threadfence();                       // my stores visible before done++
        unsigned old = atomicAdd(done, 1u);    // device-scope
        if (old == BB - 1u) {                  // last block of THIS launch
            __threadfence();
            int npT = 0; float csumT = 0.0f;
            for (int i = 0; i < BB; i++) { npT += num_pos[i]; csumT += cpart[i]; }
            const float Nt = (float)npT;
            out[0] = s_lsum / Nt;
            out[1] = csumT / Nt;
        }
    }
}

extern "C" void kernel_launch(void* const* d_in, const int* in_sizes, int n_in,
                              void* d_out, int out_size, void* d_ws, size_t ws_size,
                              hipStream_t stream) {
    const float* loc_data  = (const float*)d_in[0];  // [64,8732,4]
    const float* conf_data = (const float*)d_in[1];  // [64,8732,81]
    const float* dboxes    = (const float*)d_in[2];  // [8732,4]
    const float* tboxes    = (const float*)d_in[3];  // [64,50,4]
    const int*   tlabels   = (const int*)d_in[4];    // [64,50]
    float* out = (float*)d_out;

    // ws: lse[B*D] f32 | conf_t[B*D] u8 | lpart[MBX*BB] | num_pos[BB] |
    //     cpart[BB] | done[1]   (done zeroed by k_main block 0)
    float*         lse     = (float*)d_ws;
    unsigned char* conf_t  = (unsigned char*)(lse + (size_t)BB * DD);
    float*         lpart   = (float*)(conf_t + (size_t)BB * DD);  // B*D % 4 == 0
    int*           num_pos = (int*)(lpart + MBX * BB);
    float*         cpart   = (float*)(num_pos + BB);
    unsigned*      done    = (unsigned*)(cpart + BB);

    hipLaunchKernelGGL(k_main, dim3(CE_GRID + MBX * BB), dim3(256), 0, stream,
                       conf_data, loc_data, dboxes, tboxes, tlabels,
                       lse, conf_t, lpart, done);
    hipLaunchKernelGGL(k_tail, dim3(BB), dim3(256), 0, stream,
                       lse, conf_t, conf_data, lpart, num_pos, cpart, done, out);
}

// Round 5
// 314.780 us; speedup vs baseline: 3.4179x; 1.0113x over previous
//
#include <hip/hip_runtime.h>
#include <math.h>

#define BB 64
#define DD 8732
#define CC 81
#define NN 50
#define TROWS 64                    // rows per tile
#define TFL4  1296                  // 64*81/4 float4 per tile (20736 B)
#define CE_GRID 1024                // stream blocks: 4 per CU
#define MBX 35                      // match x-chunks: ceil(8732/256)
#define NTILES (BB * DD / TROWS)    // 8732 exactly

// ---------------- k_main: LSE stream (blocks < CE_GRID) || match (rest) -----
// Stream part: verbatim R4 (proven). Match part: verbatim R4 PLUS the
// x_ct gather: conf_data[r*81+ct] is loaded here (uncoalesced, but hidden
// under the stream's latency shadow) and stored coalesced to xct[r], so
// k_tail never touches conf_data. Block 0 zeroes `done` for k_tail.
__global__ __launch_bounds__(256, 8) void k_main(
    const float* __restrict__ conf_data,  // [B,D,C]
    const float* __restrict__ loc_data,   // [B,D,4]
    const float* __restrict__ dboxes,     // [D,4]
    const float* __restrict__ tboxes,     // [B,N,4]
    const int*   __restrict__ tlabels,    // [B,N]
    float* __restrict__ lse,              // [B*D] out
    unsigned char* __restrict__ conf_t,   // [B*D] out
    float* __restrict__ xct,              // [B*D] out: conf_data[r*81+ct]
    float* __restrict__ lpart,            // [MBX*BB] out: smooth-L1 partials
    unsigned* __restrict__ done)          // [1] zeroed here each launch
{
    __shared__ float4 sbuf[TFL4];         // 20736 B (allocated for all blocks)
    __shared__ float  s_m[4];
    const int tid = threadIdx.x;

    if (blockIdx.x == 0 && tid == 0) *done = 0u;   // reset for k_tail

    if (blockIdx.x < CE_GRID) {
        // ---------------- streaming LSE ----------------
        const int lane = tid & 63;
        const int w    = tid >> 6;        // wave in block (0..3)
        const int q    = lane >> 4;       // quarter (0..3)
        const int s    = lane & 15;       // sublane within quarter

        float4 r0, r1, r2, r3, r4, r5;
        int t = blockIdx.x;
        {
            const float4* src = (const float4*)conf_data + (size_t)t * TFL4;
            r0 = src[tid];
            r1 = src[tid + 256];
            r2 = src[tid + 512];
            r3 = src[tid + 768];
            r4 = src[tid + 1024];
            if (tid < 16) r5 = src[1280 + tid];
        }
        for (; t < NTILES; t += CE_GRID) {
            __syncthreads();                      // prior compute done
            sbuf[tid]        = r0;                // vmcnt wait lands here
            sbuf[tid + 256]  = r1;
            sbuf[tid + 512]  = r2;
            sbuf[tid + 768]  = r3;
            sbuf[tid + 1024] = r4;
            if (tid < 16) sbuf[1280 + tid] = r5;
            const int tn = t + CE_GRID;
            if (tn < NTILES) {                    // issue next tile's loads NOW
                const float4* src = (const float4*)conf_data + (size_t)tn * TFL4;
                r0 = src[tid];
                r1 = src[tid + 256];
                r2 = src[tid + 512];
                r3 = src[tid + 768];
                r4 = src[tid + 1024];
                if (tid < 16) r5 = src[1280 + tid];
            }
            __syncthreads();                      // tile t visible in LDS

            const float* sb = (const float*)sbuf;
            #pragma unroll
            for (int i = 0; i < 4; i++) {
                const int lr = w * 16 + i * 4 + q;        // local row 0..63
                const float* row = sb + lr * CC;
                float x0 = row[s];
                float x1 = row[s + 16];
                float x2 = row[s + 32];
                float x3 = row[s + 48];
                float x4 = row[s + 64];
                float x5 = (s == 0) ? row[80] : 0.0f;

                float e = __expf(x0) + __expf(x1) + __expf(x2) + __expf(x3) + __expf(x4);
                if (s == 0) e += __expf(x5);
                #pragma unroll
                for (int off = 1; off < 16; off <<= 1) e += __shfl_xor(e, off);
                if (s == 0) lse[t * TROWS + lr] = __logf(e);
            }
        }
    } else {
        // ---------------- match (R4 body + x_ct gather) ----------------
        const int bid2 = blockIdx.x - CE_GRID;    // 0..MBX*BB-1
        const int b    = bid2 / MBX;
        const int bx   = bid2 - b * MBX;
        const int d    = bx * 256 + tid;
        const bool active = (d < DD);
        const int dc   = active ? d : (DD - 1);   // clamp: uniform execution

        const float* __restrict__ tb = tboxes + b * (NN * 4);  // uniform -> s_load

        const float4 db = ((const float4*)dboxes)[dc];
        const float dx1 = db.x, dy1 = db.y, dx2 = db.z, dy2 = db.w;
        const float dArea = (dx1 - dx2) * (dy1 - dy2);

        float bestIoU = -1.0f;
        int   bestN   = 0;
        #pragma unroll 10
        for (int n = 0; n < NN; n++) {
            const float tx1 = tb[n * 4 + 0];
            const float ty1 = tb[n * 4 + 1];
            const float tx2 = tb[n * 4 + 2];
            const float ty2 = tb[n * 4 + 3];
            const float area = (tx1 - tx2) * (ty1 - ty2);   // == reference _area
            const float lx = fmaxf(tx1, dx1), ly = fmaxf(ty1, dy1);
            const float rx = fminf(tx2, dx2), ry = fminf(ty2, dy2);
            const float w2 = fmaxf(rx - lx, 0.0f), h2 = fmaxf(ry - ly, 0.0f);
            const float inter = w2 * h2;
            const float iou = inter / (area + dArea - inter);  // IEEE, ref order
            if (iou > bestIoU) { bestIoU = iou; bestN = n; }   // first-max
        }

        int ct = 0;
        if (!(bestIoU < 0.5f)) ct = tlabels[b * NN + bestN] + 1;
        const bool pos = active && (ct > 0);
        const size_t r = (size_t)b * DD + d;
        if (active) {
            conf_t[r] = (unsigned char)ct;
            xct[r]    = conf_data[r * CC + (size_t)ct];  // hidden gather
        }

        float ll = 0.0f;
        if (pos) {
            const float bx1 = tb[bestN * 4 + 0], by1 = tb[bestN * 4 + 1];
            const float bx2 = tb[bestN * 4 + 2], by2 = tb[bestN * 4 + 3];
            const float dw = dx2 - dx1, dh = dy2 - dy1;
            const float t0 = ((bx1 - dx1) + (bx2 - dx2)) * 0.5f * 10.0f / dw;
            const float t1 = ((by1 - dy1) + (by2 - dy2)) * 0.5f * 10.0f / dh;
            const float t2 = __logf((bx2 - bx1) / dw) * 5.0f;
            const float t3 = __logf((by2 - by1) / dh) * 5.0f;
            const float4 ld = ((const float4*)loc_data)[r];
            float xs[4] = {ld.x - t0, ld.y - t1, ld.z - t2, ld.w - t3};
            #pragma unroll
            for (int k = 0; k < 4; k++) {
                float ax = fabsf(xs[k]);
                ll += (ax < 1.0f) ? 0.5f * xs[k] * xs[k] : ax - 0.5f;
            }
        }
        for (int off = 32; off > 0; off >>= 1) ll += __shfl_down(ll, off);
        if ((tid & 63) == 0) s_m[tid >> 6] = ll;
        __syncthreads();
        if (tid == 0) lpart[bid2] = s_m[0] + s_m[1] + s_m[2] + s_m[3];
    }
}

// ---------------- k_tail: CE rebuild + pos stats + top-K + finalize ----------
// Per batch b: ce = fmax(lse[r] - xct[r], 0) -- all coalesced reads, no
// conf_data gather (moved to k_main's match blocks). num_pos counted from
// conf_t. Top-K via binary search on float bit patterns. done zeroed by
// k_main; last-arriving block finalizes (R1's proven pattern).
__global__ __launch_bounds__(256) void k_tail(
    const float* __restrict__ lse,        // [B*D]
    const unsigned char* __restrict__ conf_t,
    const float* __restrict__ xct,        // [B*D]
    const float* __restrict__ lpart,      // [MBX*BB]
    int*   __restrict__ num_pos,          // [B]  (plain stores)
    float* __restrict__ cpart,            // [B]  (plain stores)
    unsigned* __restrict__ done,          // [1]  (zeroed by k_main)
    float* __restrict__ out)              // [2]
{
    const int b   = blockIdx.x;
    const int tid = threadIdx.x;
    __shared__ int   s_cnt;
    __shared__ float s_sum;
    __shared__ float s_lsum;
    __shared__ int   s_np;

    // grand-total loss_l (redundant per block; 9 loads/thread)
    float lp = 0.0f;
    for (int j = tid; j < MBX * BB; j += 256) lp += lpart[j];
    for (int off = 32; off > 0; off >>= 1) lp += __shfl_down(lp, off);
    if (tid == 0) { s_lsum = 0.0f; s_np = 0; }
    __syncthreads();
    if ((tid & 63) == 0) atomicAdd(&s_lsum, lp);

    // per-row CE rebuild (bit-exact); count positives
    unsigned vv[35];                      // 35*256 = 8960 >= 8732
    float lcp = 0.0f;                     // positive-row CE partial
    int   myp = 0;
    #pragma unroll
    for (int j = 0; j < 35; j++) {
        const int i = tid + j * 256;
        if (i < DD) {
            const size_t r = (size_t)b * DD + i;
            const int   ct = conf_t[r];
            const float ce = fmaxf(lse[r] - xct[r], 0.0f);
            if (ct > 0) { lcp += ce; myp++; vv[j] = 0u; }
            else        { vv[j] = __float_as_uint(ce); }
        } else vv[j] = 0u;
    }
    for (int off = 32; off > 0; off >>= 1) myp += __shfl_down(myp, off);
    if ((tid & 63) == 0) atomicAdd(&s_np, myp);
    __syncthreads();
    const int np = s_np;
    const int K  = min(3 * np, DD);
    if (tid == 0) num_pos[b] = np;

    // K-th largest via binary search on bit patterns (values >= 0)
    unsigned ustar = 0xFFFFFFFFu;
    float    thr   = 0.0f;
    if (K > 0) {
        unsigned lo = 0u, hi = 0x7F800000u;
        while (lo < hi) {
            unsigned mid = lo + ((hi - lo) >> 1);
            int c = 0;
            #pragma unroll
            for (int j = 0; j < 35; j++) c += (vv[j] > mid) ? 1 : 0;
            for (int off = 32; off > 0; off >>= 1) c += __shfl_down(c, off);
            if (tid == 0) s_cnt = 0;
            __syncthreads();
            if ((tid & 63) == 0) atomicAdd(&s_cnt, c);
            __syncthreads();
            if (s_cnt >= K) lo = mid + 1; else hi = mid;
            __syncthreads();
        }
        ustar = lo;
        thr   = __uint_as_float(ustar);
    }

    // block loss_c partial = pos CE + sum(v > thr) + (K - cnt_gt)*thr
    float sum = lcp;
    int   cgt = 0;
    if (K > 0) {
        #pragma unroll
        for (int j = 0; j < 35; j++) {
            if (vv[j] > ustar) { sum += __uint_as_float(vv[j]); cgt++; }
        }
    }
    for (int off = 32; off > 0; off >>= 1) {
        sum += __shfl_down(sum, off);
        cgt += __shfl_down(cgt, off);
    }
    if (tid == 0) { s_sum = 0.0f; s_cnt = 0; }
    __syncthreads();
    if ((tid & 63) == 0) { atomicAdd(&s_sum, sum); atomicAdd(&s_cnt, cgt); }
    __syncthreads();
    if (tid == 0) {
        cpart[b] = s_sum + ((K > 0) ? (float)(K - s_cnt) * thr : 0.0f);
        __threadfence();                       // my stores visible before done++
        unsigned old = atomicAdd(done, 1u);    // device-scope
        if (old == BB - 1u) {                  // last block of THIS launch
            __threadfence();
            int npT = 0; float csumT = 0.0f;
            for (int i = 0; i < BB; i++) { npT += num_pos[i]; csumT += cpart[i]; }
            const float Nt = (float)npT;
            out[0] = s_lsum / Nt;
            out[1] = csumT / Nt;
        }
    }
}

extern "C" void kernel_launch(void* const* d_in, const int* in_sizes, int n_in,
                              void* d_out, int out_size, void* d_ws, size_t ws_size,
                              hipStream_t stream) {
    const float* loc_data  = (const float*)d_in[0];  // [64,8732,4]
    const float* conf_data = (const float*)d_in[1];  // [64,8732,81]
    const float* dboxes    = (const float*)d_in[2];  // [8732,4]
    const float* tboxes    = (const float*)d_in[3];  // [64,50,4]
    const int*   tlabels   = (const int*)d_in[4];    // [64,50]
    float* out = (float*)d_out;

    // ws: lse[B*D] f32 | xct[B*D] f32 | conf_t[B*D] u8 | lpart[MBX*BB] |
    //     num_pos[BB] | cpart[BB] | done[1]  (done zeroed by k_main block 0)
    float*         lse     = (float*)d_ws;
    float*         xct     = lse + (size_t)BB * DD;
    unsigned char* conf_t  = (unsigned char*)(xct + (size_t)BB * DD);
    float*         lpart   = (float*)(conf_t + (size_t)BB * DD);  // B*D % 4 == 0
    int*           num_pos = (int*)(lpart + MBX * BB);
    float*         cpart   = (float*)(num_pos + BB);
    unsigned*      done    = (unsigned*)(cpart + BB);

    hipLaunchKernelGGL(k_main, dim3(CE_GRID + MBX * BB), dim3(256), 0, stream,
                       conf_data, loc_data, dboxes, tboxes, tlabels,
                       lse, conf_t, xct, lpart, done);
    hipLaunchKernelGGL(k_tail, dim3(BB), dim3(256), 0, stream,
                       lse, conf_t, xct, lpart, num_pos, cpart, done, out);
}

// Round 6
// 304.548 us; speedup vs baseline: 3.5327x; 1.0336x over previous
//
#include <hip/hip_runtime.h>
#include <math.h>

#define BB 64
#define DD 8732
#define CC 81
#define NN 50
#define NROWS (BB * DD)             // 558848 rows
#define CE_GRID 1024                // stream blocks
#define NGRP (CE_GRID * 16)         // 16384 row-groups in stream part
#define MBX 35                      // match x-chunks: ceil(8732/256)

// ---------------- k_main: LSE stream (blocks < CE_GRID) || match (rest) -----
// Stream part v3: NO LDS, NO barriers. Each 16-lane group reads its row
// directly from global (lanes s..s+64 stride-16 scalar loads = 4x64B fully
// consumed segments per wave instr). e-summation + shuffle order is byte-
// identical to R5 (bit-exact lse). Residency now VGPR-capped (8 blocks/CU),
// not LDS-capped (7), and there is zero barrier/prefetch latency to hide.
// Match part: verbatim R5 (proven), incl. the hidden x_ct gather.
// Block 0 zeroes `done` for k_tail.
__global__ __launch_bounds__(256, 8) void k_main(
    const float* __restrict__ conf_data,  // [B,D,C]
    const float* __restrict__ loc_data,   // [B,D,4]
    const float* __restrict__ dboxes,     // [D,4]
    const float* __restrict__ tboxes,     // [B,N,4]
    const int*   __restrict__ tlabels,    // [B,N]
    float* __restrict__ lse,              // [B*D] out
    unsigned char* __restrict__ conf_t,   // [B*D] out
    float* __restrict__ xct,              // [B*D] out: conf_data[r*81+ct]
    float* __restrict__ lpart,            // [MBX*BB] out: smooth-L1 partials
    unsigned* __restrict__ done)          // [1] zeroed here each launch
{
    __shared__ float s_m[4];              // match-part cross-wave reduce only
    const int tid = threadIdx.x;

    if (blockIdx.x == 0 && tid == 0) *done = 0u;   // reset for k_tail

    if (blockIdx.x < CE_GRID) {
        // ---------------- streaming LSE, direct-global ----------------
        const int s   = tid & 15;                  // sublane within group
        const int gid = blockIdx.x * 16 + (tid >> 4);  // global group id

        for (int base = gid * 4; base < NROWS; base += NGRP * 4) {
            #pragma unroll
            for (int i = 0; i < 4; i++) {
                const int r = base + i;            // NROWS%4==0 -> in range
                const float* row = conf_data + (size_t)r * CC;
                float x0 = row[s];
                float x1 = row[s + 16];
                float x2 = row[s + 32];
                float x3 = row[s + 48];
                float x4 = row[s + 64];
                float x5 = (s == 0) ? row[80] : 0.0f;

                float e = __expf(x0) + __expf(x1) + __expf(x2) + __expf(x3) + __expf(x4);
                if (s == 0) e += __expf(x5);
                #pragma unroll
                for (int off = 1; off < 16; off <<= 1) e += __shfl_xor(e, off);
                if (s == 0) lse[r] = __logf(e);
            }
        }
    } else {
        // ---------------- match (R5 body, verbatim) ----------------
        const int bid2 = blockIdx.x - CE_GRID;    // 0..MBX*BB-1
        const int b    = bid2 / MBX;
        const int bx   = bid2 - b * MBX;
        const int d    = bx * 256 + tid;
        const bool active = (d < DD);
        const int dc   = active ? d : (DD - 1);   // clamp: uniform execution

        const float* __restrict__ tb = tboxes + b * (NN * 4);  // uniform -> s_load

        const float4 db = ((const float4*)dboxes)[dc];
        const float dx1 = db.x, dy1 = db.y, dx2 = db.z, dy2 = db.w;
        const float dArea = (dx1 - dx2) * (dy1 - dy2);

        float bestIoU = -1.0f;
        int   bestN   = 0;
        #pragma unroll 10
        for (int n = 0; n < NN; n++) {
            const float tx1 = tb[n * 4 + 0];
            const float ty1 = tb[n * 4 + 1];
            const float tx2 = tb[n * 4 + 2];
            const float ty2 = tb[n * 4 + 3];
            const float area = (tx1 - tx2) * (ty1 - ty2);   // == reference _area
            const float lx = fmaxf(tx1, dx1), ly = fmaxf(ty1, dy1);
            const float rx = fminf(tx2, dx2), ry = fminf(ty2, dy2);
            const float w2 = fmaxf(rx - lx, 0.0f), h2 = fmaxf(ry - ly, 0.0f);
            const float inter = w2 * h2;
            const float iou = inter / (area + dArea - inter);  // IEEE, ref order
            if (iou > bestIoU) { bestIoU = iou; bestN = n; }   // first-max
        }

        int ct = 0;
        if (!(bestIoU < 0.5f)) ct = tlabels[b * NN + bestN] + 1;
        const bool pos = active && (ct > 0);
        const size_t r = (size_t)b * DD + d;
        if (active) {
            conf_t[r] = (unsigned char)ct;
            xct[r]    = conf_data[r * CC + (size_t)ct];  // hidden gather
        }

        float ll = 0.0f;
        if (pos) {
            const float bx1 = tb[bestN * 4 + 0], by1 = tb[bestN * 4 + 1];
            const float bx2 = tb[bestN * 4 + 2], by2 = tb[bestN * 4 + 3];
            const float dw = dx2 - dx1, dh = dy2 - dy1;
            const float t0 = ((bx1 - dx1) + (bx2 - dx2)) * 0.5f * 10.0f / dw;
            const float t1 = ((by1 - dy1) + (by2 - dy2)) * 0.5f * 10.0f / dh;
            const float t2 = __logf((bx2 - bx1) / dw) * 5.0f;
            const float t3 = __logf((by2 - by1) / dh) * 5.0f;
            const float4 ld = ((const float4*)loc_data)[r];
            float xs[4] = {ld.x - t0, ld.y - t1, ld.z - t2, ld.w - t3};
            #pragma unroll
            for (int k = 0; k < 4; k++) {
                float ax = fabsf(xs[k]);
                ll += (ax < 1.0f) ? 0.5f * xs[k] * xs[k] : ax - 0.5f;
            }
        }
        for (int off = 32; off > 0; off >>= 1) ll += __shfl_down(ll, off);
        if ((tid & 63) == 0) s_m[tid >> 6] = ll;
        __syncthreads();
        if (tid == 0) lpart[bid2] = s_m[0] + s_m[1] + s_m[2] + s_m[3];
    }
}

// ---------------- k_tail: CE rebuild + pos stats + top-K + finalize ----------
// Verbatim R5 (proven). Per batch b: ce = fmax(lse[r]-xct[r],0), all
// coalesced; num_pos from conf_t; top-K via bit-pattern binary search;
// done zeroed by k_main; last-arriving block finalizes.
__global__ __launch_bounds__(256) void k_tail(
    const float* __restrict__ lse,        // [B*D]
    const unsigned char* __restrict__ conf_t,
    const float* __restrict__ xct,        // [B*D]
    const float* __restrict__ lpart,      // [MBX*BB]
    int*   __restrict__ num_pos,          // [B]  (plain stores)
    float* __restrict__ cpart,            // [B]  (plain stores)
    unsigned* __restrict__ done,          // [1]  (zeroed by k_main)
    float* __restrict__ out)              // [2]
{
    const int b   = blockIdx.x;
    const int tid = threadIdx.x;
    __shared__ int   s_cnt;
    __shared__ float s_sum;
    __shared__ float s_lsum;
    __shared__ int   s_np;

    // grand-total loss_l (redundant per block; 9 loads/thread)
    float lp = 0.0f;
    for (int j = tid; j < MBX * BB; j += 256) lp += lpart[j];
    for (int off = 32; off > 0; off >>= 1) lp += __shfl_down(lp, off);
    if (tid == 0) { s_lsum = 0.0f; s_np = 0; }
    __syncthreads();
    if ((tid & 63) == 0) atomicAdd(&s_lsum, lp);

    // per-row CE rebuild (bit-exact); count positives
    unsigned vv[35];                      // 35*256 = 8960 >= 8732
    float lcp = 0.0f;                     // positive-row CE partial
    int   myp = 0;
    #pragma unroll
    for (int j = 0; j < 35; j++) {
        const int i = tid + j * 256;
        if (i < DD) {
            const size_t r = (size_t)b * DD + i;
            const int   ct = conf_t[r];
            const float ce = fmaxf(lse[r] - xct[r], 0.0f);
            if (ct > 0) { lcp += ce; myp++; vv[j] = 0u; }
            else        { vv[j] = __float_as_uint(ce); }
        } else vv[j] = 0u;
    }
    for (int off = 32; off > 0; off >>= 1) myp += __shfl_down(myp, off);
    if ((tid & 63) == 0) atomicAdd(&s_np, myp);
    __syncthreads();
    const int np = s_np;
    const int K  = min(3 * np, DD);
    if (tid == 0) num_pos[b] = np;

    // K-th largest via binary search on bit patterns (values >= 0)
    unsigned ustar = 0xFFFFFFFFu;
    float    thr   = 0.0f;
    if (K > 0) {
        unsigned lo = 0u, hi = 0x7F800000u;
        while (lo < hi) {
            unsigned mid = lo + ((hi - lo) >> 1);
            int c = 0;
            #pragma unroll
            for (int j = 0; j < 35; j++) c += (vv[j] > mid) ? 1 : 0;
            for (int off = 32; off > 0; off >>= 1) c += __shfl_down(c, off);
            if (tid == 0) s_cnt = 0;
            __syncthreads();
            if ((tid & 63) == 0) atomicAdd(&s_cnt, c);
            __syncthreads();
            if (s_cnt >= K) lo = mid + 1; else hi = mid;
            __syncthreads();
        }
        ustar = lo;
        thr   = __uint_as_float(ustar);
    }

    // block loss_c partial = pos CE + sum(v > thr) + (K - cnt_gt)*thr
    float sum = lcp;
    int   cgt = 0;
    if (K > 0) {
        #pragma unroll
        for (int j = 0; j < 35; j++) {
            if (vv[j] > ustar) { sum += __uint_as_float(vv[j]); cgt++; }
        }
    }
    for (int off = 32; off > 0; off >>= 1) {
        sum += __shfl_down(sum, off);
        cgt += __shfl_down(cgt, off);
    }
    if (tid == 0) { s_sum = 0.0f; s_cnt = 0; }
    __syncthreads();
    if ((tid & 63) == 0) { atomicAdd(&s_sum, sum); atomicAdd(&s_cnt, cgt); }
    __syncthreads();
    if (tid == 0) {
        cpart[b] = s_sum + ((K > 0) ? (float)(K - s_cnt) * thr : 0.0f);
        __threadfence();                       // my stores visible before done++
        unsigned old = atomicAdd(done, 1u);    // device-scope
        if (old == BB - 1u) {                  // last block of THIS launch
            __threadfence();
            int npT = 0; float csumT = 0.0f;
            for (int i = 0; i < BB; i++) { npT += num_pos[i]; csumT += cpart[i]; }
            const float Nt = (float)npT;
            out[0] = s_lsum / Nt;
            out[1] = csumT / Nt;
        }
    }
}

extern "C" void kernel_launch(void* const* d_in, const int* in_sizes, int n_in,
                              void* d_out, int out_size, void* d_ws, size_t ws_size,
                              hipStream_t stream) {
    const float* loc_data  = (const float*)d_in[0];  // [64,8732,4]
    const float* conf_data = (const float*)d_in[1];  // [64,8732,81]
    const float* dboxes    = (const float*)d_in[2];  // [8732,4]
    const float* tboxes    = (const float*)d_in[3];  // [64,50,4]
    const int*   tlabels   = (const int*)d_in[4];    // [64,50]
    float* out = (float*)d_out;

    // ws: lse[B*D] f32 | xct[B*D] f32 | conf_t[B*D] u8 | lpart[MBX*BB] |
    //     num_pos[BB] | cpart[BB] | done[1]  (done zeroed by k_main block 0)
    float*         lse     = (float*)d_ws;
    float*         xct     = lse + (size_t)BB * DD;
    unsigned char* conf_t  = (unsigned char*)(xct + (size_t)BB * DD);
    float*         lpart   = (float*)(conf_t + (size_t)BB * DD);  // B*D % 4 == 0
    int*           num_pos = (int*)(lpart + MBX * BB);
    float*         cpart   = (float*)(num_pos + BB);
    unsigned*      done    = (unsigned*)(cpart + BB);

    hipLaunchKernelGGL(k_main, dim3(CE_GRID + MBX * BB), dim3(256), 0, stream,
                       conf_data, loc_data, dboxes, tboxes, tlabels,
                       lse, conf_t, xct, lpart, done);
    hipLaunchKernelGGL(k_tail, dim3(BB), dim3(256), 0, stream,
                       lse, conf_t, xct, lpart, num_pos, cpart, done, out);
}